// Round 1
// baseline (2144.577 us; speedup 1.0000x reference)
//
#include <hip/hip_runtime.h>
#include <hip/hip_bf16.h>

#define DIM 32
#define EPS 1e-5f
#define SCAT_BLOCKS 256
#define SCAT_THREADS 1024

// ---------------------------------------------------------------------------
// Kernel 1: fused edge + node scatter-sum with per-block LDS privatization.
// LDS: 1024 segments x 32 dims fp32 = 128KB + 4KB counts (gfx950 has 160KB).
// 8 lanes per row, float4 loads (1KB per wave = peak-BW pattern).
// ---------------------------------------------------------------------------
__global__ __launch_bounds__(SCAT_THREADS, 1)
void scatter_kernel(const int* __restrict__ eidx0,      // edge_index row 0 [E]
                    const int* __restrict__ batch,      // [N]
                    const float4* __restrict__ ea4,     // edge_attr as float4 [E*8]
                    const float4* __restrict__ x4,      // x as float4 [N*8]
                    float* __restrict__ gsum_e, float* __restrict__ gcnt_e,
                    float* __restrict__ gsum_v, float* __restrict__ gcnt_v,
                    int E, int N, int B)
{
    __shared__ float lsum[1024 * DIM];   // 128 KB
    __shared__ float lcnt[1024];         // 4 KB

    const int tid   = threadIdx.x;
    const int lane8 = tid & 7;
    const int rot   = (tid >> 3) & 3;    // per-group component rotation -> 2-way LDS banking (free)
    const int gid   = (blockIdx.x * SCAT_THREADS + tid) >> 3;
    const int gstride = (SCAT_BLOCKS * SCAT_THREADS) >> 3;   // 32768 groups

    for (int i = tid; i < B * DIM; i += SCAT_THREADS) lsum[i] = 0.f;
    if (tid < B) lcnt[tid] = 0.f;
    __syncthreads();

    // ---- edges: seg = batch[eidx0[e]] ----
    {
        int e = gid;
        int src0 = 0; float4 v0 = make_float4(0.f, 0.f, 0.f, 0.f);
        if (e < E) { src0 = eidx0[e]; v0 = ea4[(size_t)e * 8 + lane8]; }
        while (e < E) {
            int en = e + gstride;                      // 1-deep prefetch of next iter
            int src1 = 0; float4 v1 = make_float4(0.f, 0.f, 0.f, 0.f);
            if (en < E) { src1 = eidx0[en]; v1 = ea4[(size_t)en * 8 + lane8]; }
            int seg  = batch[src0];
            int base = seg * DIM + lane8 * 4;
            #pragma unroll
            for (int s = 0; s < 4; ++s) {
                int c = (s + rot) & 3;
                float val = (c == 0) ? v0.x : (c == 1) ? v0.y : (c == 2) ? v0.z : v0.w;
                atomicAdd(&lsum[base + c], val);       // ds_add_f32
            }
            if (lane8 == 0) atomicAdd(&lcnt[seg], 1.0f);
            e = en; src0 = src1; v0 = v1;
        }
    }
    __syncthreads();
    for (int i = tid; i < B * DIM; i += SCAT_THREADS) unsafeAtomicAdd(&gsum_e[i], lsum[i]);
    if (tid < B) unsafeAtomicAdd(&gcnt_e[tid], lcnt[tid]);
    __syncthreads();
    for (int i = tid; i < B * DIM; i += SCAT_THREADS) lsum[i] = 0.f;
    if (tid < B) lcnt[tid] = 0.f;
    __syncthreads();

    // ---- nodes: seg = batch[n] ----
    {
        int n = gid;
        int s0 = 0; float4 v0 = make_float4(0.f, 0.f, 0.f, 0.f);
        if (n < N) { s0 = batch[n]; v0 = x4[(size_t)n * 8 + lane8]; }
        while (n < N) {
            int nn = n + gstride;
            int s1 = 0; float4 v1 = make_float4(0.f, 0.f, 0.f, 0.f);
            if (nn < N) { s1 = batch[nn]; v1 = x4[(size_t)nn * 8 + lane8]; }
            int base = s0 * DIM + lane8 * 4;
            #pragma unroll
            for (int s = 0; s < 4; ++s) {
                int c = (s + rot) & 3;
                float val = (c == 0) ? v0.x : (c == 1) ? v0.y : (c == 2) ? v0.z : v0.w;
                atomicAdd(&lsum[base + c], val);
            }
            if (lane8 == 0) atomicAdd(&lcnt[s0], 1.0f);
            n = nn; s0 = s1; v0 = v1;
        }
    }
    __syncthreads();
    for (int i = tid; i < B * DIM; i += SCAT_THREADS) unsafeAtomicAdd(&gsum_v[i], lsum[i]);
    if (tid < B) unsafeAtomicAdd(&gcnt_v[tid], lcnt[tid]);
}

// ---------------------------------------------------------------------------
// Kernel 2: tail MLP. One block, 1024 threads = 1 thread per batch row.
// comb_T is [96][B] in ws so GEMM loads are coalesced. W/bias read with
// wave-uniform addresses (scalarizes to s_load). BN stats via per-wave
// column reductions; normalization folded into the next GEMM's load.
// ---------------------------------------------------------------------------
__global__ __launch_bounds__(1024, 1)
void tail_kernel(const float* __restrict__ gsum_e, const float* __restrict__ gcnt_e,
                 const float* __restrict__ gsum_v, const float* __restrict__ gcnt_v,
                 const float* __restrict__ state,
                 const float* __restrict__ W1, const float* __restrict__ b1,
                 const float* __restrict__ g1, const float* __restrict__ be1,
                 const float* __restrict__ W2, const float* __restrict__ b2,
                 const float* __restrict__ g2, const float* __restrict__ be2,
                 const float* __restrict__ W3, const float* __restrict__ b3,
                 const float* __restrict__ g3, const float* __restrict__ be3,
                 float* __restrict__ comb_T,   // [96*B]
                 float* __restrict__ hT,       // [32*B], reused across layers
                 float* __restrict__ out,      // [B*32]
                 int B)
{
    __shared__ float sscale[DIM], soff[DIM];
    const int tid = threadIdx.x;
    const int b   = tid;

    // build comb_T = [u_e ; u_v ; state] transposed (columns contiguous)
    for (int k = 0; k < DIM; ++k)
        for (int bb = tid; bb < B; bb += 1024)
            comb_T[k * B + bb] = gsum_e[bb * DIM + k] / fmaxf(gcnt_e[bb], 1.f);
    for (int k = 0; k < DIM; ++k)
        for (int bb = tid; bb < B; bb += 1024)
            comb_T[(k + 32) * B + bb] = gsum_v[bb * DIM + k] / fmaxf(gcnt_v[bb], 1.f);
    for (int k = 0; k < DIM; ++k)
        for (int bb = tid; bb < B; bb += 1024)
            comb_T[(k + 64) * B + bb] = state[bb * DIM + k];
    __syncthreads();

    // BN stats over hT (pre-norm activations), writes sscale/soff so that
    // normalized value = fmaf(v, sscale[j], soff[j]).
#define BN_STATS(GAMMA, BETA) do {                                           \
        __syncthreads();                                                     \
        int wv_ = tid >> 6, ln_ = tid & 63;                                  \
        for (int rep_ = 0; rep_ < 2; ++rep_) {                               \
            int j_ = wv_ * 2 + rep_;                                         \
            float s_ = 0.f, q_ = 0.f;                                        \
            for (int i_ = ln_; i_ < B; i_ += 64) {                           \
                float v_ = hT[j_ * B + i_]; s_ += v_; q_ = fmaf(v_, v_, q_); \
            }                                                                \
            for (int off_ = 32; off_ > 0; off_ >>= 1) {                      \
                s_ += __shfl_xor(s_, off_); q_ += __shfl_xor(q_, off_);      \
            }                                                                \
            if (ln_ == 0) {                                                  \
                float m_ = s_ / (float)B;                                    \
                float var_ = q_ / (float)B - m_ * m_;                        \
                float sc_ = GAMMA[j_] * rsqrtf(var_ + EPS);                  \
                sscale[j_] = sc_; soff[j_] = BETA[j_] - m_ * sc_;            \
            }                                                                \
        }                                                                    \
        __syncthreads();                                                     \
    } while (0)

    float h[DIM], h2[DIM];

    // ---- layer 1: relu(comb @ W1 + b1) ----
    #pragma unroll
    for (int j = 0; j < DIM; ++j) h[j] = b1[j];
    if (b < B) {
        for (int k = 0; k < 96; ++k) {
            float c = comb_T[k * B + b];
            #pragma unroll
            for (int j = 0; j < DIM; ++j) h[j] = fmaf(c, W1[k * DIM + j], h[j]);
        }
        #pragma unroll
        for (int j = 0; j < DIM; ++j) { h[j] = fmaxf(h[j], 0.f); hT[j * B + b] = h[j]; }
    }
    BN_STATS(g1, be1);

    // ---- layer 2: relu(bn1(h) @ W2 + b2), bn1 folded into load ----
    #pragma unroll
    for (int j = 0; j < DIM; ++j) h2[j] = b2[j];
    if (b < B) {
        for (int k = 0; k < DIM; ++k) {
            float c = fmaf(hT[k * B + b], sscale[k], soff[k]);
            #pragma unroll
            for (int j = 0; j < DIM; ++j) h2[j] = fmaf(c, W2[k * DIM + j], h2[j]);
        }
        #pragma unroll
        for (int j = 0; j < DIM; ++j) { h2[j] = fmaxf(h2[j], 0.f); hT[j * B + b] = h2[j]; }
    }
    BN_STATS(g2, be2);

    // ---- layer 3: bn2(h2) @ W3 + b3 (no relu) ----
    #pragma unroll
    for (int j = 0; j < DIM; ++j) h[j] = b3[j];
    if (b < B) {
        for (int k = 0; k < DIM; ++k) {
            float c = fmaf(hT[k * B + b], sscale[k], soff[k]);
            #pragma unroll
            for (int j = 0; j < DIM; ++j) h[j] = fmaf(c, W3[k * DIM + j], h[j]);
        }
        #pragma unroll
        for (int j = 0; j < DIM; ++j) hT[j * B + b] = h[j];
    }
    BN_STATS(g3, be3);

    // ---- final normalize + store ----
    if (b < B) {
        #pragma unroll
        for (int j = 0; j < DIM; ++j) out[b * DIM + j] = fmaf(h[j], sscale[j], soff[j]);
    }
#undef BN_STATS
}

extern "C" void kernel_launch(void* const* d_in, const int* in_sizes, int n_in,
                              void* d_out, int out_size, void* d_ws, size_t ws_size,
                              hipStream_t stream)
{
    const float* x     = (const float*)d_in[0];
    const int*   eidx  = (const int*)  d_in[1];   // row 0 = first E entries
    const float* ea    = (const float*)d_in[2];
    const float* state = (const float*)d_in[3];
    const int*   batch = (const int*)  d_in[4];
    const float* W1 = (const float*)d_in[5];  const float* b1  = (const float*)d_in[6];
    const float* g1 = (const float*)d_in[7];  const float* be1 = (const float*)d_in[8];
    const float* W2 = (const float*)d_in[9];  const float* b2  = (const float*)d_in[10];
    const float* g2 = (const float*)d_in[11]; const float* be2 = (const float*)d_in[12];
    const float* W3 = (const float*)d_in[13]; const float* b3  = (const float*)d_in[14];
    const float* g3 = (const float*)d_in[15]; const float* be3 = (const float*)d_in[16];
    float* out = (float*)d_out;

    const int N = in_sizes[0] / DIM;
    const int E = in_sizes[2] / DIM;
    const int B = in_sizes[3] / DIM;

    float* ws     = (float*)d_ws;
    float* gsum_e = ws;                         // B*32
    float* gcnt_e = gsum_e + (size_t)B * DIM;   // B
    float* gsum_v = gcnt_e + B;                 // B*32
    float* gcnt_v = gsum_v + (size_t)B * DIM;   // B
    float* comb_T = gcnt_v + B;                 // 96*B
    float* hT     = comb_T + (size_t)96 * B;    // 32*B

    // zero the accumulators (ws is poisoned 0xAA before every call)
    size_t zero_bytes = (size_t)(2 * (B * DIM + B)) * sizeof(float);
    hipMemsetAsync(d_ws, 0, zero_bytes, stream);

    scatter_kernel<<<SCAT_BLOCKS, SCAT_THREADS, 0, stream>>>(
        eidx, batch, (const float4*)ea, (const float4*)x,
        gsum_e, gcnt_e, gsum_v, gcnt_v, E, N, B);

    tail_kernel<<<1, 1024, 0, stream>>>(
        gsum_e, gcnt_e, gsum_v, gcnt_v, state,
        W1, b1, g1, be1, W2, b2, g2, be2, W3, b3, g3, be3,
        comb_T, hT, out, B);
}